// Round 3
// baseline (6899.701 us; speedup 1.0000x reference)
//
#include <hip/hip_runtime.h>
#include <hip/hip_bf16.h>

#define B_ 2
#define S_ 2048
#define D_ 1024
#define H_ 16
#define HD_ 64

// C = X @ W^T + bias, with head-split store: out[(b*H+h), s, hd] (f32)
// X: [4096,1024] f32 row-major, W: [1024,1024] f32 row-major.
// Both operands K-contiguous (A row . W row), BM=BN=64, BK=16, 256 thr, 4x4 micro-tile.
__global__ __launch_bounds__(256) void proj_kernel(
    const float* __restrict__ X, const float* __restrict__ W,
    const float* __restrict__ bias, float* __restrict__ out)
{
    __shared__ float As[64][17];
    __shared__ float Bs[64][17];
    const int t  = threadIdx.x;
    const int m0 = blockIdx.y * 64;
    const int n0 = blockIdx.x * 64;
    const int tx = t & 15, ty = t >> 4;
    const int lrow = t >> 2;
    const int lseg = (t & 3) * 4;
    float acc[4][4] = {};

    for (int k0 = 0; k0 < D_; k0 += 16) {
        float4 a4 = *(const float4*)(X + (size_t)(m0 + lrow) * D_ + k0 + lseg);
        float4 b4 = *(const float4*)(W + (size_t)(n0 + lrow) * D_ + k0 + lseg);
        As[lrow][lseg + 0] = a4.x; As[lrow][lseg + 1] = a4.y;
        As[lrow][lseg + 2] = a4.z; As[lrow][lseg + 3] = a4.w;
        Bs[lrow][lseg + 0] = b4.x; Bs[lrow][lseg + 1] = b4.y;
        Bs[lrow][lseg + 2] = b4.z; Bs[lrow][lseg + 3] = b4.w;
        __syncthreads();
#pragma unroll
        for (int kk = 0; kk < 16; ++kk) {
            float a_[4], b_[4];
#pragma unroll
            for (int i = 0; i < 4; ++i) a_[i] = As[ty * 4 + i][kk];
#pragma unroll
            for (int j = 0; j < 4; ++j) b_[j] = Bs[tx * 4 + j][kk];
#pragma unroll
            for (int i = 0; i < 4; ++i)
#pragma unroll
                for (int j = 0; j < 4; ++j) acc[i][j] += a_[i] * b_[j];
        }
        __syncthreads();
    }

    float bb[4];
#pragma unroll
    for (int j = 0; j < 4; ++j) bb[j] = bias[n0 + tx * 4 + j];
    const int h = n0 >> 6;  // BN=64 aligned to head boundary -> head fixed per block
#pragma unroll
    for (int i = 0; i < 4; ++i) {
        int row = m0 + ty * 4 + i;     // 0..4095 = b*S + s
        int b = row >> 11;
        int s = row & 2047;
        float* op = out + (((size_t)(b * H_ + h)) * S_ + s) * HD_ + tx * 4;
#pragma unroll
        for (int j = 0; j < 4; ++j) op[j] = acc[i][j] + bb[j];
    }
}

// One block per (q-row, bh). scores -> mask -> softmax -> write attn (f32) -> ctx (f32).
// Faithful mask quirk: group bh uses mask[bh % B].
__global__ __launch_bounds__(256) void attn_kernel(
    const float* __restrict__ qw, const float* __restrict__ kw, const float* __restrict__ vw,
    const int* __restrict__ mask,
    float* __restrict__ out_ctx, float* __restrict__ out_attn)
{
    __shared__ float qs[HD_];
    __shared__ float ss[S_];
    __shared__ float red[16];
    __shared__ float cpart[4][HD_];

    const int t = threadIdx.x;
    const int qrow = blockIdx.x;
    const int bh = blockIdx.y;
    const size_t bhbase = (size_t)bh * S_ * HD_;

    if (t < HD_) qs[t] = qw[bhbase + (size_t)qrow * HD_ + t];
    __syncthreads();

    const int* mrow = mask + ((size_t)(bh % B_) * S_ + qrow) * S_;
    const float4* q4 = (const float4*)qs;

    float sc[8];
    float lmax = -3e38f;
#pragma unroll
    for (int it = 0; it < 8; ++it) {
        int k = t + it * 256;
        const float4* kr = (const float4*)(kw + bhbase + (size_t)k * HD_);
        float acc = 0.f;
#pragma unroll
        for (int d = 0; d < 16; ++d) {
            float4 kv = kr[d];
            float4 qv = q4[d];
            acc += qv.x * kv.x + qv.y * kv.y + qv.z * kv.z + qv.w * kv.w;
        }
        float s = mrow[k] ? -1e30f : acc * 0.125f;
        sc[it] = s;
        lmax = fmaxf(lmax, s);
    }
#pragma unroll
    for (int off = 32; off > 0; off >>= 1) lmax = fmaxf(lmax, __shfl_down(lmax, off));
    if ((t & 63) == 0) red[t >> 6] = lmax;
    __syncthreads();
    const float smax = fmaxf(fmaxf(red[0], red[1]), fmaxf(red[2], red[3]));

    float lsum = 0.f;
#pragma unroll
    for (int it = 0; it < 8; ++it) {
        float e = __expf(sc[it] - smax);
        ss[t + it * 256] = e;
        lsum += e;
    }
#pragma unroll
    for (int off = 32; off > 0; off >>= 1) lsum += __shfl_down(lsum, off);
    if ((t & 63) == 0) red[8 + (t >> 6)] = lsum;
    __syncthreads();
    const float inv = 1.f / (red[8] + red[9] + red[10] + red[11]);

    float* arow = out_attn + ((size_t)bh * S_ + qrow) * S_;
#pragma unroll
    for (int it = 0; it < 8; ++it) {
        arow[t + it * 256] = ss[t + it * 256] * inv;
    }

    // ctx: thread t -> hd = t&63, k-chunk = t>>6 (4 chunks of 512)
    const int hd = t & 63;
    const int chunk = t >> 6;
    float acc = 0.f;
    const float* vp = vw + bhbase + (size_t)chunk * 512 * HD_ + hd;
    const float* sp = ss + chunk * 512;
    for (int k = 0; k < 512; ++k) acc += sp[k] * vp[(size_t)k * HD_];
    cpart[chunk][hd] = acc * inv;
    __syncthreads();
    if (t < HD_) {
        float sum = cpart[0][t] + cpart[1][t] + cpart[2][t] + cpart[3][t];
        int b = bh >> 4;   // bh / H
        int h = bh & 15;   // bh % H
        out_ctx[((size_t)(b * S_ + qrow)) * D_ + h * HD_ + t] = sum;
    }
}

extern "C" void kernel_launch(void* const* d_in, const int* in_sizes, int n_in,
                              void* d_out, int out_size, void* d_ws, size_t ws_size,
                              hipStream_t stream) {
    (void)in_sizes; (void)n_in; (void)out_size; (void)ws_size;
    const float* q_in = (const float*)d_in[0];
    const float* k_in = (const float*)d_in[1];
    const float* v_in = (const float*)d_in[2];
    const int*   mask = (const int*)d_in[3];
    const float* Wq = (const float*)d_in[4];
    const float* bq = (const float*)d_in[5];
    const float* Wk = (const float*)d_in[6];
    const float* bk = (const float*)d_in[7];
    const float* Wv = (const float*)d_in[8];
    const float* bv = (const float*)d_in[9];

    const size_t qkv_elems = (size_t)B_ * H_ * S_ * HD_;  // 4,194,304
    float* qw = (float*)d_ws;
    float* kw = qw + qkv_elems;
    float* vw = kw + qkv_elems;

    float* ctx  = (float*)d_out;
    float* attn = ctx + (size_t)B_ * S_ * D_;

    dim3 pgrid(D_ / 64, (B_ * S_) / 64), pblock(256);
    proj_kernel<<<pgrid, pblock, 0, stream>>>(q_in, Wq, bq, qw);
    proj_kernel<<<pgrid, pblock, 0, stream>>>(k_in, Wk, bk, kw);
    proj_kernel<<<pgrid, pblock, 0, stream>>>(v_in, Wv, bv, vw);

    dim3 agrid(S_, B_ * H_), ablock(256);
    attn_kernel<<<agrid, ablock, 0, stream>>>(qw, kw, vw, mask, ctx, attn);
}